// Round 14
// baseline (168.858 us; speedup 1.0000x reference)
//
#include <hip/hip_runtime.h>
#include <math.h>

#define N_ 16
#define H_ 512
#define W_ 512
#define HW_ (H_ * W_)
#define BAND 4              // output rows per block
#define GAMMA_ 2.0f

__device__ __forceinline__ float wave_reduce(float v) {
#pragma unroll
    for (int off = 32; off > 0; off >>= 1)
        v += __shfl_down(v, off, 64);
    return v;
}

// Pass A: sum(weight_raw). Needs only box(x0), box(x2), box(d^2), d = x0-x2.
__global__ __launch_bounds__(256) void passA(const float* __restrict__ x,
                                             float* __restrict__ scalars) {
    __shared__ float rowbuf[2][3][W_];   // 12288 B, double-buffered
    __shared__ float red[4];

    const int tid = threadIdx.x;
    const int c0 = tid * 2;
    const int y0 = blockIdx.x * BAND;
    const int b = blockIdx.y;
    const float* xb = x + (size_t)b * (3 * HW_);
    const float inv81 = 1.0f / 81.0f;

    float va[3][2];
#pragma unroll
    for (int f = 0; f < 3; ++f) va[f][0] = va[f][1] = 0.0f;

    auto apply = [&](float2 a0, float2 a2, float sgn) {
#pragma unroll
        for (int i = 0; i < 2; ++i) {
            float x0 = i ? a0.y : a0.x;
            float x2 = i ? a2.y : a2.x;
            float d = x0 - x2;
            va[0][i] = fmaf(sgn, x0, va[0][i]);
            va[1][i] = fmaf(sgn, x2, va[1][i]);
            va[2][i] = fmaf(sgn, d * d, va[2][i]);
        }
    };

#pragma unroll
    for (int k = 0; k < 9; ++k) {
        int rr = (y0 - 4 + k) & (H_ - 1);
        const float* p = xb + rr * W_ + c0;
        apply(*(const float2*)(p), *(const float2*)(p + 2 * HW_), 1.0f);
    }

    float accwr = 0.0f;
    float2 na0, na2, pa0, pa2;

    for (int it = 0; it < BAND; ++it) {
        const int y = y0 + it;
        const int slot = it & 1;
#pragma unroll
        for (int f = 0; f < 3; ++f)
            *(float2*)&rowbuf[slot][f][c0] = make_float2(va[f][0], va[f][1]);

        const bool more = (it + 1 < BAND);
        if (more) {  // issue next-row loads BEFORE the barrier
            const float* pa = xb + ((y + 5) & (H_ - 1)) * W_ + c0;
            const float* ps = xb + ((y - 4) & (H_ - 1)) * W_ + c0;
            na0 = *(const float2*)(pa); na2 = *(const float2*)(pa + 2 * HW_);
            pa0 = *(const float2*)(ps); pa2 = *(const float2*)(ps + 2 * HW_);
        }
        __syncthreads();

        float hs[3][2];
#pragma unroll
        for (int f = 0; f < 3; ++f) {
            float2 v[5];
#pragma unroll
            for (int j = 0; j < 5; ++j)
                v[j] = *(const float2*)&rowbuf[slot][f][(c0 + 2 * j - 4) & (W_ - 1)];
            float s0 = ((v[0].x + v[0].y) + (v[1].x + v[1].y)) +
                       ((v[2].x + v[2].y) + (v[3].x + v[3].y)) + v[4].x;
            hs[f][0] = s0;
            hs[f][1] = s0 - v[0].x + v[4].y;
        }
#pragma unroll
        for (int i = 0; i < 2; ++i) {
            float md = (hs[0][i] - hs[1][i]) * inv81;
            accwr += (2.0f / 3.0f) * (hs[2][i] * inv81 - md * md);
        }

        if (more) {
            apply(na0, na2, 1.0f);
            apply(pa0, pa2, -1.0f);
        }
    }

    float s = wave_reduce(accwr);
    if ((tid & 63) == 0) red[tid >> 6] = s;
    __syncthreads();
    if (tid == 0) atomicAdd(&scalars[0], (red[0] + red[1]) + (red[2] + red[3]));
}

// Pass B: recompute all 6 fields; w = exp(-coef*wr); reduce sum(w), sum(w*diff).
__global__ __launch_bounds__(256) void passB(const float* __restrict__ x,
                                             float* __restrict__ scalars) {
    __shared__ float rowbuf[2][6][W_];   // 24576 B, double-buffered
    __shared__ float red[8];

    const int tid = threadIdx.x;
    const int c0 = tid * 2;
    const int y0 = blockIdx.x * BAND;
    const int b = blockIdx.y;
    const float* xb = x + (size_t)b * (3 * HW_);
    const float inv81 = 1.0f / 81.0f;
    const float coef = GAMMA_ * (float)HW_ / scalars[0];

    float vs[6][2];
#pragma unroll
    for (int f = 0; f < 6; ++f) vs[f][0] = vs[f][1] = 0.0f;

    auto apply = [&](float2 a0, float2 a1, float2 a2, float sgn) {
#pragma unroll
        for (int i = 0; i < 2; ++i) {
            float x0 = i ? a0.y : a0.x;
            float x1 = i ? a1.y : a1.x;
            float x2 = i ? a2.y : a2.x;
            float yv = (x0 + x1 + x2) * (1.0f / 3.0f);
            float d = x0 - x2;
            vs[0][i] = fmaf(sgn, x0, vs[0][i]);
            vs[1][i] = fmaf(sgn, x1, vs[1][i]);
            vs[2][i] = fmaf(sgn, x2, vs[2][i]);
            vs[3][i] = fmaf(sgn, x0 * x0 + x1 * x1 + x2 * x2, vs[3][i]);
            vs[4][i] = fmaf(sgn, yv * yv, vs[4][i]);
            vs[5][i] = fmaf(sgn, d * d, vs[5][i]);
        }
    };

#pragma unroll
    for (int k = 0; k < 9; ++k) {
        int rr = (y0 - 4 + k) & (H_ - 1);
        const float* p = xb + rr * W_ + c0;
        apply(*(const float2*)(p), *(const float2*)(p + HW_), *(const float2*)(p + 2 * HW_), 1.0f);
    }

    float accw = 0.0f, accwd = 0.0f;
    float2 na0, na1, na2, pa0, pa1, pa2;

    for (int it = 0; it < BAND; ++it) {
        const int y = y0 + it;
        const int slot = it & 1;
#pragma unroll
        for (int f = 0; f < 6; ++f)
            *(float2*)&rowbuf[slot][f][c0] = make_float2(vs[f][0], vs[f][1]);

        const bool more = (it + 1 < BAND);
        if (more) {  // issue next-row loads BEFORE the barrier
            const float* pa = xb + ((y + 5) & (H_ - 1)) * W_ + c0;
            const float* ps = xb + ((y - 4) & (H_ - 1)) * W_ + c0;
            na0 = *(const float2*)(pa);
            na1 = *(const float2*)(pa + HW_);
            na2 = *(const float2*)(pa + 2 * HW_);
            pa0 = *(const float2*)(ps);
            pa1 = *(const float2*)(ps + HW_);
            pa2 = *(const float2*)(ps + 2 * HW_);
        }
        __syncthreads();

        float hs[6][2];
#pragma unroll
        for (int f = 0; f < 6; ++f) {
            float2 v[5];
#pragma unroll
            for (int j = 0; j < 5; ++j)
                v[j] = *(const float2*)&rowbuf[slot][f][(c0 + 2 * j - 4) & (W_ - 1)];
            float s0 = ((v[0].x + v[0].y) + (v[1].x + v[1].y)) +
                       ((v[2].x + v[2].y) + (v[3].x + v[3].y)) + v[4].x;
            hs[f][0] = s0;
            hs[f][1] = s0 - v[0].x + v[4].y;
        }

#pragma unroll
        for (int i = 0; i < 2; ++i) {
            float B0 = hs[0][i] * inv81, B1 = hs[1][i] * inv81, B2 = hs[2][i] * inv81;
            float alpha = (hs[3][i] * inv81 - (B0 * B0 + B1 * B1 + B2 * B2)) * (1.0f / 3.0f);
            float my = (B0 + B1 + B2) * (1.0f / 3.0f);
            float beta = hs[4][i] * inv81 - my * my;
            float md = B0 - B2;
            float wr = (2.0f / 3.0f) * (hs[5][i] * inv81 - md * md);
            float df = alpha - beta;
            float w = __expf(-coef * wr);
            accw += w;
            accwd += w * df;
        }

        if (more) {
            apply(na0, na1, na2, 1.0f);
            apply(pa0, pa1, pa2, -1.0f);
        }
    }

    float s0 = wave_reduce(accw);
    float s1 = wave_reduce(accwd);
    if ((tid & 63) == 0) {
        red[tid >> 6] = s0;
        red[4 + (tid >> 6)] = s1;
    }
    __syncthreads();
    if (tid == 0) {
        atomicAdd(&scalars[1], (red[0] + red[1]) + (red[2] + red[3]));
        atomicAdd(&scalars[2], (red[4] + red[5]) + (red[6] + red[7]));
    }
}

__global__ void final_kernel(const float* __restrict__ scalars, float* __restrict__ out) {
    out[0] = 1.5f * scalars[2] / scalars[1];
}

extern "C" void kernel_launch(void* const* d_in, const int* in_sizes, int n_in,
                              void* d_out, int out_size, void* d_ws, size_t ws_size,
                              hipStream_t stream) {
    const float* x = (const float*)d_in[0];
    float* out = (float*)d_out;
    float* scalars = (float*)d_ws;  // [0]=sum(wr), [1]=sum(w), [2]=sum(w*diff)

    hipMemsetAsync(d_ws, 0, 16, stream);

    dim3 grid(H_ / BAND, N_);   // 128 x 16 = 2048 blocks
    passA<<<grid, 256, 0, stream>>>(x, scalars);
    passB<<<grid, 256, 0, stream>>>(x, scalars);
    final_kernel<<<1, 1, 0, stream>>>(scalars, out);
}

// Round 15
// 129.396 us; speedup vs baseline: 1.3050x; 1.3050x over previous
//
#include <hip/hip_runtime.h>
#include <math.h>

#define N_ 16
#define H_ 512
#define W_ 512
#define HW_ (H_ * W_)
#define B_ 8                // band rows per wave
#define GAMMA_ 2.0f

__device__ __forceinline__ float wave_reduce(float v) {
#pragma unroll
    for (int off = 32; off > 0; off >>= 1) v += __shfl_down(v, off, 64);
    return v;
}

// Load 12 consecutive (mod W) floats: 3 aligned float4 chunks at constant
// per-thread column offsets (each chunk is contiguous; bases are %4==0 so no
// chunk straddles the wrap).
__device__ __forceinline__ void load12(const float* __restrict__ row,
                                       int cbm, int cb0, int cb4, float v[12]) {
    float4 a = *(const float4*)(row + cbm);
    float4 b = *(const float4*)(row + cb0);
    float4 c = *(const float4*)(row + cb4);
    v[0] = a.x; v[1] = a.y; v[2] = a.z;  v[3] = a.w;
    v[4] = b.x; v[5] = b.y; v[6] = b.z;  v[7] = b.w;
    v[8] = c.x; v[9] = c.y; v[10] = c.z; v[11] = c.w;
}

// Sliding 9-tap sums: h[j] = sum v[j..j+8], j=0..3 (cols c0+j own window).
__device__ __forceinline__ void hsum9(const float v[12], float h[4]) {
    float s = ((v[0] + v[1]) + (v[2] + v[3])) + ((v[4] + v[5]) + (v[6] + v[7])) + v[8];
    h[0] = s;
    s += v[9]  - v[0]; h[1] = s;
    s += v[10] - v[1]; h[2] = s;
    s += v[11] - v[2]; h[3] = s;
}

// passB per-row fields: x0, x1, x2, g = (x0^2+x1^2+x2^2)/3 - y^2, d^2.
__device__ __forceinline__ void fields_hsum5(const float a0[12], const float a1[12],
                                             const float a2[12], float h0[4], float h1[4],
                                             float h2[4], float hg[4], float hd[4]) {
    float fg[12], fd[12];
#pragma unroll
    for (int i = 0; i < 12; ++i) {
        float q3 = (a0[i] * a0[i] + a1[i] * a1[i] + a2[i] * a2[i]) * (1.0f / 3.0f);
        float yv = (a0[i] + a1[i] + a2[i]) * (1.0f / 3.0f);
        fg[i] = q3 - yv * yv;
        float dd = a0[i] - a2[i];
        fd[i] = dd * dd;
    }
    hsum9(a0, h0); hsum9(a1, h1); hsum9(a2, h2); hsum9(fg, hg); hsum9(fd, hd);
}

// wave decode shared by both passes
#define DECODE()                                                        \
    const int tid = threadIdx.x;                                        \
    const int lane = tid & 63;                                          \
    const int l = ((int)blockIdx.x & 7) * 64 + ((int)blockIdx.x >> 3);  \
    const int g = l * 4 + (tid >> 6);          /* 0..2047 */            \
    const int half = g & 1;                                             \
    const int bg = g >> 1;                                              \
    const int b = bg >> 6;                                              \
    const int y0 = (bg & 63) * B_;                                      \
    const int c0 = half * 256 + lane * 4;                               \
    const int cbm = (c0 - 4) & (W_ - 1);                                \
    const int cb4 = (c0 + 4) & (W_ - 1);                                \
    const float* xb = x + (size_t)b * (3 * HW_);                        \
    const float inv81 = 1.0f / 81.0f;

// Pass A: sum(weight_raw) = (2/3) * [ sum(d^2)  -  sum(box(d)^2) ]
// (circular box with unit-sum kernel: sum_p box(f)(p) == sum_p f(p), exact).
// Only ONE stencil field (d = x0 - x2) + an elementwise own-pixel d^2 sum.
__global__ __launch_bounds__(256) void passA(const float* __restrict__ x,
                                             float* __restrict__ scalars) {
    __shared__ float red[4];
    DECODE();

    float vsd[4] = {0.f, 0.f, 0.f, 0.f};

#pragma unroll
    for (int k = 0; k < 9; ++k) {  // prologue rows y0-4..y0+4
        int rr = (y0 - 4 + k) & (H_ - 1);
        const float* r = xb + rr * W_;
        float a0[12], a2[12], fd[12], h[4];
        load12(r, cbm, c0, cb4, a0);
        load12(r + 2 * HW_, cbm, c0, cb4, a2);
#pragma unroll
        for (int i = 0; i < 12; ++i) fd[i] = a0[i] - a2[i];
        hsum9(fd, h);
#pragma unroll
        for (int j = 0; j < 4; ++j) vsd[j] += h[j];
    }

    float acc = 0.0f;
    for (int it = 0; it < B_; ++it) {
        const int y = y0 + it;
        float ra0[12], ra2[12], rs0[12], rs2[12];
        const bool more = (it + 1 < B_);
        if (more) {  // issue loads before the (register-only) epilogue
            const float* pa = xb + ((y + 5) & (H_ - 1)) * W_;
            const float* ps = xb + ((y - 4) & (H_ - 1)) * W_;
            load12(pa, cbm, c0, cb4, ra0);
            load12(pa + 2 * HW_, cbm, c0, cb4, ra2);
            load12(ps, cbm, c0, cb4, rs0);
            load12(ps + 2 * HW_, cbm, c0, cb4, rs2);
        }
#pragma unroll
        for (int j = 0; j < 4; ++j) {
            float bd = vsd[j] * inv81;
            acc = fmaf(bd, bd, acc);
        }
        if (more) {
            float fa[12], fs[12], ha[4], hs[4];
#pragma unroll
            for (int i = 0; i < 12; ++i) {
                fa[i] = ra0[i] - ra2[i];
                fs[i] = rs0[i] - rs2[i];
            }
            hsum9(fa, ha); hsum9(fs, hs);
#pragma unroll
            for (int j = 0; j < 4; ++j) vsd[j] += ha[j] - hs[j];
        }
    }

    // own-pixel sum of d^2 over the band (L2-hot re-read, 2 float4 per row)
    float d2acc = 0.0f;
#pragma unroll
    for (int r = 0; r < B_; ++r) {
        const float* pr = xb + (y0 + r) * W_ + c0;
        float4 q0 = *(const float4*)(pr);
        float4 q2 = *(const float4*)(pr + 2 * HW_);
        float d0 = q0.x - q2.x, d1 = q0.y - q2.y;
        float d2v = q0.z - q2.z, d3 = q0.w - q2.w;
        d2acc += (d0 * d0 + d1 * d1) + (d2v * d2v + d3 * d3);
    }

    float part = (2.0f / 3.0f) * (d2acc - acc);
    float s = wave_reduce(part);
    if (lane == 0) red[tid >> 6] = s;
    __syncthreads();
    if (tid == 0) atomicAdd(&scalars[0], (red[0] + red[1]) + (red[2] + red[3]));
}

// Pass B: 5 stencil fields; w = exp(-coef*wr); reduce sum(w), sum(w*diff).
// diff = box(g) - (B0^2+B1^2+B2^2)/3 + ((B0+B1+B2)/3)^2;  wr = 2/3*(box(d2)-(B0-B2)^2)
__global__ __launch_bounds__(256) void passB(const float* __restrict__ x,
                                             float* __restrict__ scalars) {
    __shared__ float red[8];
    DECODE();
    const float coef = GAMMA_ * (float)HW_ / scalars[0];

    float vs0[4] = {0.f, 0.f, 0.f, 0.f}, vs1[4] = {0.f, 0.f, 0.f, 0.f};
    float vs2[4] = {0.f, 0.f, 0.f, 0.f}, vsg[4] = {0.f, 0.f, 0.f, 0.f};
    float vsd[4] = {0.f, 0.f, 0.f, 0.f};

#pragma unroll
    for (int k = 0; k < 9; ++k) {  // prologue
        int rr = (y0 - 4 + k) & (H_ - 1);
        const float* r = xb + rr * W_;
        float a0[12], a1[12], a2[12], h0[4], h1[4], h2[4], hg[4], hd[4];
        load12(r, cbm, c0, cb4, a0);
        load12(r + HW_, cbm, c0, cb4, a1);
        load12(r + 2 * HW_, cbm, c0, cb4, a2);
        fields_hsum5(a0, a1, a2, h0, h1, h2, hg, hd);
#pragma unroll
        for (int j = 0; j < 4; ++j) {
            vs0[j] += h0[j]; vs1[j] += h1[j]; vs2[j] += h2[j];
            vsg[j] += hg[j]; vsd[j] += hd[j];
        }
    }

    float accw = 0.0f, accwd = 0.0f;
    for (int it = 0; it < B_; ++it) {
        const int y = y0 + it;
        float ra0[12], ra1[12], ra2[12], rs0[12], rs1[12], rs2[12];
        const bool more = (it + 1 < B_);
        if (more) {  // loads in flight across the register-only epilogue
            const float* pa = xb + ((y + 5) & (H_ - 1)) * W_;
            const float* ps = xb + ((y - 4) & (H_ - 1)) * W_;
            load12(pa, cbm, c0, cb4, ra0);
            load12(pa + HW_, cbm, c0, cb4, ra1);
            load12(pa + 2 * HW_, cbm, c0, cb4, ra2);
            load12(ps, cbm, c0, cb4, rs0);
            load12(ps + HW_, cbm, c0, cb4, rs1);
            load12(ps + 2 * HW_, cbm, c0, cb4, rs2);
        }
#pragma unroll
        for (int j = 0; j < 4; ++j) {
            float B0 = vs0[j] * inv81, B1 = vs1[j] * inv81, B2v = vs2[j] * inv81;
            float boxg = vsg[j] * inv81, boxd2 = vsd[j] * inv81;
            float By = (B0 + B1 + B2v) * (1.0f / 3.0f);
            float s2 = (B0 * B0 + B1 * B1 + B2v * B2v) * (1.0f / 3.0f);
            float diff = boxg - s2 + By * By;
            float md = B0 - B2v;
            float wr = (2.0f / 3.0f) * (boxd2 - md * md);
            float w = __expf(-coef * wr);
            accw += w;
            accwd = fmaf(w, diff, accwd);
        }
        if (more) {
            float ha0[4], ha1[4], ha2[4], hag[4], had[4];
            float hb0[4], hb1[4], hb2[4], hbg[4], hbd[4];
            fields_hsum5(ra0, ra1, ra2, ha0, ha1, ha2, hag, had);
            fields_hsum5(rs0, rs1, rs2, hb0, hb1, hb2, hbg, hbd);
#pragma unroll
            for (int j = 0; j < 4; ++j) {
                vs0[j] += ha0[j] - hb0[j];
                vs1[j] += ha1[j] - hb1[j];
                vs2[j] += ha2[j] - hb2[j];
                vsg[j] += hag[j] - hbg[j];
                vsd[j] += had[j] - hbd[j];
            }
        }
    }

    float sw = wave_reduce(accw);
    float sd = wave_reduce(accwd);
    if (lane == 0) {
        red[tid >> 6] = sw;
        red[4 + (tid >> 6)] = sd;
    }
    __syncthreads();
    if (tid == 0) {
        atomicAdd(&scalars[1], (red[0] + red[1]) + (red[2] + red[3]));
        atomicAdd(&scalars[2], (red[4] + red[5]) + (red[6] + red[7]));
    }
}

__global__ void final_kernel(const float* __restrict__ scalars, float* __restrict__ out) {
    out[0] = 1.5f * scalars[2] / scalars[1];
}

extern "C" void kernel_launch(void* const* d_in, const int* in_sizes, int n_in,
                              void* d_out, int out_size, void* d_ws, size_t ws_size,
                              hipStream_t stream) {
    const float* x = (const float*)d_in[0];
    float* out = (float*)d_out;
    float* scalars = (float*)d_ws;  // [0]=sum(wr), [1]=sum(w), [2]=sum(w*diff)

    hipMemsetAsync(d_ws, 0, 16, stream);

    // 512 blocks x 4 waves = 2048 waves: 16 img x 64 bands x 2 half-widths
    passA<<<512, 256, 0, stream>>>(x, scalars);
    passB<<<512, 256, 0, stream>>>(x, scalars);
    final_kernel<<<1, 1, 0, stream>>>(scalars, out);
}